// Round 1
// baseline (268.019 us; speedup 1.0000x reference)
//
#include <hip/hip_runtime.h>
#include <math.h>

#define D_INC   16
#define NODES   32
#define HID     32
#define HS      48
#define WSZ     48
#define H_IN    96
#define W_IN    96
#define N_B     32
#define TILE_ROWS 16
#define HALO_ROWS (TILE_ROWS + 2)
#define HALO_COLS (WSZ + 2)

// ---------------- Kernel A: 3x3 maxpool, stride 2, pad 1 ----------------
__global__ __launch_bounds__(256) void maxpool_kernel(
    const float* __restrict__ x, float* __restrict__ P)
{
    int idx = blockIdx.x * 256 + threadIdx.x;
    const int total = N_B * D_INC * HS * WSZ;
    if (idx >= total) return;
    int c  = idx % WSZ;
    int t  = idx / WSZ;
    int r  = t % HS;
    int nd = t / HS;                       // n*D + d
    const float* xb = x + (size_t)nd * (H_IN * W_IN);
    int r0 = 2 * r - 1, c0 = 2 * c - 1;
    float m = -INFINITY;
    #pragma unroll
    for (int i = 0; i < 3; ++i) {
        int rr = r0 + i;
        if (rr < 0 || rr >= H_IN) continue;
        #pragma unroll
        for (int j = 0; j < 3; ++j) {
            int cc = c0 + j;
            if (cc < 0 || cc >= W_IN) continue;
            m = fmaxf(m, xb[rr * W_IN + cc]);
        }
    }
    P[idx] = m;
}

// ------------- Kernel B: per-node depthwise conv + MLP, fused -------------
// grid: (3 row-tiles, 32 nodes, 32 batch)  block: 256 threads
// LDS: P tile with halo, 16ch x 18r x 50c fp32 = 57.6 KB -> 2 blocks/CU
__global__ __launch_bounds__(256) void fused_kernel(
    const float* __restrict__ P,
    const float* __restrict__ S,     // (O, D, 3, 3)
    const float* __restrict__ W1,    // (O, D, HID)
    const float* __restrict__ b1,    // (O, HID)
    const float* __restrict__ W2,    // (O, HID)
    const float* __restrict__ b2,    // (O,)
    float* __restrict__ out)         // (N, O, HS, WSZ)
{
    __shared__ float Pt[D_INC][HALO_ROWS][HALO_COLS];

    const int tile = blockIdx.x;     // 0..2
    const int o    = blockIdx.y;     // node
    const int n    = blockIdx.z;     // batch
    const int tid  = threadIdx.x;
    const int r0   = tile * TILE_ROWS;

    const float* Pn = P + (size_t)n * D_INC * (HS * WSZ);

    // ---- stage P tile (+halo, zero-padded) into LDS ----
    for (int idx = tid; idx < D_INC * HALO_ROWS * HALO_COLS; idx += 256) {
        int c = idx % HALO_COLS;
        int t = idx / HALO_COLS;
        int r = t % HALO_ROWS;
        int d = t / HALO_ROWS;
        int gr = r0 + r - 1;
        int gc = c - 1;
        float v = 0.f;
        if (gr >= 0 && gr < HS && gc >= 0 && gc < WSZ)
            v = Pn[d * (HS * WSZ) + gr * WSZ + gc];
        Pt[d][r][c] = v;
    }
    __syncthreads();

    // block-uniform weight pointers -> scalar (s_load) accesses
    const float* So  = S  + o * (D_INC * 9);
    const float* W1o = W1 + o * (D_INC * HID);
    const float* b1o = b1 + o * HID;
    const float* W2o = W2 + o * HID;
    const float  b2o = b2[o];

    // each thread: 3 consecutive pixels in one row
    const int row = tid >> 4;          // 0..15 (tile-local row)
    const int c0  = (tid & 15) * 3;    // first pixel col

    // ---- depthwise 3x3 conv: M[pixel][channel] ----
    float M[3][D_INC];
    #pragma unroll
    for (int pp = 0; pp < 3; ++pp)
        #pragma unroll
        for (int d = 0; d < D_INC; ++d) M[pp][d] = 0.f;

    #pragma unroll
    for (int d = 0; d < D_INC; ++d) {
        float p[3][5];
        #pragma unroll
        for (int i = 0; i < 3; ++i)
            #pragma unroll
            for (int j = 0; j < 5; ++j)
                p[i][j] = Pt[d][row + i][c0 + j];   // pixel (row,c0+j-1) halo coords
        #pragma unroll
        for (int pp = 0; pp < 3; ++pp)
            #pragma unroll
            for (int i = 0; i < 3; ++i)
                #pragma unroll
                for (int j = 0; j < 3; ++j)
                    M[pp][d] = fmaf(So[d * 9 + i * 3 + j], p[i][pp + j], M[pp][d]);
    }

    // ---- per-pixel MLP 16 -> 32 -> 1 ----
    const size_t outbase =
        (((size_t)n * NODES + o) * HS + (r0 + row)) * WSZ + c0;
    #pragma unroll
    for (int pp = 0; pp < 3; ++pp) {
        float h[HID];
        #pragma unroll
        for (int j = 0; j < HID; ++j) h[j] = b1o[j];
        #pragma unroll
        for (int d = 0; d < D_INC; ++d) {
            const float md = M[pp][d];
            #pragma unroll
            for (int j = 0; j < HID; ++j)
                h[j] = fmaf(md, W1o[d * HID + j], h[j]);
        }
        float y = b2o;
        #pragma unroll
        for (int j = 0; j < HID; ++j)
            y = fmaf(fmaxf(h[j], 0.f), W2o[j], y);
        out[outbase + pp] = fmaxf(y, 0.f);
    }
}

extern "C" void kernel_launch(void* const* d_in, const int* in_sizes, int n_in,
                              void* d_out, int out_size, void* d_ws, size_t ws_size,
                              hipStream_t stream)
{
    const float* x  = (const float*)d_in[0];
    const float* S  = (const float*)d_in[1];
    const float* W1 = (const float*)d_in[2];
    const float* b1 = (const float*)d_in[3];
    const float* W2 = (const float*)d_in[4];
    const float* b2 = (const float*)d_in[5];
    float* out = (float*)d_out;
    float* P   = (float*)d_ws;           // 32*16*48*48 fp32 = 4.72 MB

    const int pool_total = N_B * D_INC * HS * WSZ;
    maxpool_kernel<<<(pool_total + 255) / 256, 256, 0, stream>>>(x, P);

    dim3 grid(HS / TILE_ROWS, NODES, N_B);   // (3, 32, 32)
    fused_kernel<<<grid, 256, 0, stream>>>(P, S, W1, b1, W2, b2, out);
}

// Round 2
// 168.501 us; speedup vs baseline: 1.5906x; 1.5906x over previous
//
#include <hip/hip_runtime.h>
#include <math.h>

#define D_INC   16
#define NODES   32
#define HID     32
#define HS      48
#define WSZ     48
#define H_IN    96
#define W_IN    96
#define N_B     32
#define TILE_ROWS 16
#define HALO_ROWS (TILE_ROWS + 2)   // 18
#define HALO_COLS 50                // 1 + 48 + 1
#define PH_CH   8                   // channels staged per phase (2 phases)

// ---------------- Kernel A: 3x3 maxpool, stride 2, pad 1 ----------------
__global__ __launch_bounds__(256) void maxpool_kernel(
    const float* __restrict__ x, float* __restrict__ P)
{
    int idx = blockIdx.x * 256 + threadIdx.x;
    const int total = N_B * D_INC * HS * WSZ;
    if (idx >= total) return;
    int c  = idx % WSZ;
    int t  = idx / WSZ;
    int r  = t % HS;
    int nd = t / HS;                       // n*D + d
    const float* xb = x + (size_t)nd * (H_IN * W_IN);
    int r0 = 2 * r - 1, c0 = 2 * c - 1;
    float m = -INFINITY;
    #pragma unroll
    for (int i = 0; i < 3; ++i) {
        int rr = r0 + i;
        if (rr < 0 || rr >= H_IN) continue;
        #pragma unroll
        for (int j = 0; j < 3; ++j) {
            int cc = c0 + j;
            if (cc < 0 || cc >= W_IN) continue;
            m = fmaxf(m, xb[rr * W_IN + cc]);
        }
    }
    P[idx] = m;
}

// ------------- Kernel B: per-node depthwise conv + MLP, fused -------------
// grid: (3 row-tiles, 32 nodes, 32 batch)  block: 256 threads
// LDS: 8ch x 18r x 50c fp32 = 28.8 KB -> 5 blocks/CU (20 waves, was 8)
__global__ __launch_bounds__(256) void fused_kernel(
    const float* __restrict__ P,
    const float* __restrict__ S,     // (O, D, 3, 3)
    const float* __restrict__ W1,    // (O, D, HID)
    const float* __restrict__ b1,    // (O, HID)
    const float* __restrict__ W2,    // (O, HID)
    const float* __restrict__ b2,    // (O,)
    float* __restrict__ out)         // (N, O, HS, WSZ)
{
    __shared__ float Pt[PH_CH][HALO_ROWS][HALO_COLS];

    const int tile = blockIdx.x;     // 0..2
    const int o    = blockIdx.y;     // node
    const int n    = blockIdx.z;     // batch
    const int tid  = threadIdx.x;
    const int r0   = tile * TILE_ROWS;

    const float* Pn = P + (size_t)n * D_INC * (HS * WSZ);

    // block-uniform weight pointers -> scalar (s_load) broadcast operands
    const float* So  = S  + o * (D_INC * 9);
    const float* W1o = W1 + o * (D_INC * HID);
    const float* b1o = b1 + o * HID;
    const float* W2o = W2 + o * HID;
    const float  b2o = b2[o];

    // each thread: 3 consecutive pixels in one row
    const int row = tid >> 4;          // 0..15 (tile-local row)
    const int c0  = (tid & 15) * 3;    // first pixel col

    float M[3][D_INC];
    #pragma unroll
    for (int pp = 0; pp < 3; ++pp)
        #pragma unroll
        for (int d = 0; d < D_INC; ++d) M[pp][d] = 0.f;

    #pragma unroll
    for (int ph = 0; ph < D_INC / PH_CH; ++ph) {
        // left/right pad columns are always zero (conv padding=1)
        if (tid < PH_CH * HALO_ROWS) {
            int dd = tid / HALO_ROWS, hr = tid % HALO_ROWS;
            Pt[dd][hr][0]  = 0.f;
            Pt[dd][hr][49] = 0.f;
        }
        // interior: each halo row = 48 contiguous floats = 12 float4 loads
        for (int idx = tid; idx < PH_CH * HALO_ROWS * 12; idx += 256) {
            int m  = idx % 12;
            int q  = idx / 12;
            int hr = q % HALO_ROWS;
            int dd = q / HALO_ROWS;
            int gr = r0 + hr - 1;
            float4 v = make_float4(0.f, 0.f, 0.f, 0.f);
            if (gr >= 0 && gr < HS)
                v = *(const float4*)(Pn + (ph * PH_CH + dd) * (HS * WSZ)
                                        + gr * WSZ + m * 4);
            float* dst = &Pt[dd][hr][1 + m * 4];
            dst[0] = v.x; dst[1] = v.y; dst[2] = v.z; dst[3] = v.w;
        }
        __syncthreads();

        // depthwise 3x3 conv for this channel phase
        #pragma unroll
        for (int dd = 0; dd < PH_CH; ++dd) {
            const int d = ph * PH_CH + dd;
            float p[3][5];
            #pragma unroll
            for (int i = 0; i < 3; ++i)
                #pragma unroll
                for (int j = 0; j < 5; ++j)
                    p[i][j] = Pt[dd][row + i][c0 + j];
            #pragma unroll
            for (int pp = 0; pp < 3; ++pp)
                #pragma unroll
                for (int i = 0; i < 3; ++i)
                    #pragma unroll
                    for (int j = 0; j < 3; ++j)
                        M[pp][d] = fmaf(So[d * 9 + i * 3 + j], p[i][pp + j], M[pp][d]);
        }
        __syncthreads();   // before next phase overwrites the tile
    }

    // ---- per-pixel MLP 16 -> 32 -> 1 ----
    const size_t outbase =
        (((size_t)n * NODES + o) * HS + (r0 + row)) * WSZ + c0;
    #pragma unroll
    for (int pp = 0; pp < 3; ++pp) {
        float h[HID];
        #pragma unroll
        for (int j = 0; j < HID; ++j) h[j] = b1o[j];
        #pragma unroll
        for (int d = 0; d < D_INC; ++d) {
            const float md = M[pp][d];
            #pragma unroll
            for (int j = 0; j < HID; ++j)
                h[j] = fmaf(md, W1o[d * HID + j], h[j]);
        }
        float y = b2o;
        #pragma unroll
        for (int j = 0; j < HID; ++j)
            y = fmaf(fmaxf(h[j], 0.f), W2o[j], y);
        out[outbase + pp] = fmaxf(y, 0.f);
    }
}

extern "C" void kernel_launch(void* const* d_in, const int* in_sizes, int n_in,
                              void* d_out, int out_size, void* d_ws, size_t ws_size,
                              hipStream_t stream)
{
    const float* x  = (const float*)d_in[0];
    const float* S  = (const float*)d_in[1];
    const float* W1 = (const float*)d_in[2];
    const float* b1 = (const float*)d_in[3];
    const float* W2 = (const float*)d_in[4];
    const float* b2 = (const float*)d_in[5];
    float* out = (float*)d_out;
    float* P   = (float*)d_ws;           // 32*16*48*48 fp32 = 4.72 MB

    const int pool_total = N_B * D_INC * HS * WSZ;
    maxpool_kernel<<<(pool_total + 255) / 256, 256, 0, stream>>>(x, P);

    dim3 grid(HS / TILE_ROWS, NODES, N_B);   // (3, 32, 32)
    fused_kernel<<<grid, 256, 0, stream>>>(P, S, W1, b1, W2, b2, out);
}

// Round 3
// 118.264 us; speedup vs baseline: 2.2663x; 1.4248x over previous
//
#include <hip/hip_runtime.h>
#include <math.h>

typedef __bf16 bf16;
typedef __bf16 bf16x8 __attribute__((ext_vector_type(8)));
typedef float  f32x16 __attribute__((ext_vector_type(16)));

#define D_INC 16
#define NODES 32
#define HID   32
#define HS    48
#define WSZ   48
#define NPX   (HS*WSZ)     // 2304
#define H_IN  96
#define W_IN  96
#define N_B   32

// ---------------- Kernel W: Wkron[o][s][qp][h][j] = S[o,d,t]*W1[o,d,h] ----------------
// k = 16*s + 8*qp + j  (tap-major: t = k>>4, d = k&15); k==144 -> b1[o,h]; k>144 -> 0
// memory is lane-linear for the A-fragment loads: addr = ((o*10+s)*64 + lane)*16B
__global__ __launch_bounds__(256) void wpre_kernel(
    const float* __restrict__ S, const float* __restrict__ W1,
    const float* __restrict__ b1, bf16* __restrict__ Wp)
{
    int idx = blockIdx.x * 256 + threadIdx.x;          // 32*10*2*32*8 = 163840
    if (idx >= NODES * 10 * 2 * HID * 8) return;
    int j  = idx & 7;
    int h  = (idx >> 3) & 31;
    int qp = (idx >> 8) & 1;
    int os = idx >> 9;
    int s  = os % 10;
    int o  = os / 10;
    int k  = 16 * s + 8 * qp + j;
    float v = 0.f;
    if (k < 144) {
        int t = k >> 4;        // tap index (== s)
        int d = k & 15;        // channel
        v = S[(o * D_INC + d) * 9 + t] * W1[(o * D_INC + d) * HID + h];
    } else if (k == 144) {
        v = b1[o * HID + h];   // bias row; B-side supplies constant 1.0
    }
    Wp[idx] = (bf16)v;
}

// ---------------- Kernel P: 3x3 maxpool s2 p1, output (N,48,48,16ch) bf16 ----------------
__global__ __launch_bounds__(256) void maxpool_kernel(
    const float* __restrict__ x, bf16* __restrict__ Pg)
{
    int idx = blockIdx.x * 256 + threadIdx.x;          // 32*48*48 = 73728
    if (idx >= N_B * HS * WSZ) return;
    int c = idx % WSZ;
    int t = idx / WSZ;
    int r = t % HS;
    int n = t / HS;

    float m[D_INC];
    #pragma unroll
    for (int ch = 0; ch < D_INC; ++ch) m[ch] = -INFINITY;

    #pragma unroll
    for (int dr = 0; dr < 3; ++dr) {
        int xr = 2 * r - 1 + dr;
        if (xr < 0) continue;                           // xr <= 95 always
        #pragma unroll
        for (int dc = 0; dc < 3; ++dc) {
            int xc = 2 * c - 1 + dc;
            bool ok = (xc >= 0);                        // xc <= 95 always
            #pragma unroll
            for (int ch = 0; ch < D_INC; ++ch) {
                float v = ok ? x[((size_t)(n * D_INC + ch) * H_IN + xr) * W_IN + xc]
                             : -INFINITY;
                m[ch] = fmaxf(m[ch], v);
            }
        }
    }
    union { bf16 h[16]; uint4 q[2]; } u;
    #pragma unroll
    for (int ch = 0; ch < D_INC; ++ch) u.h[ch] = (bf16)m[ch];
    uint4* dst = (uint4*)(Pg + (size_t)idx * D_INC);
    dst[0] = u.q[0];
    dst[1] = u.q[1];
}

// ---------------- Kernel G: fused (conv+MLP1) GEMM via MFMA + MLP2 epilogue ----------------
// grid (9 px-chunks, 32 batch, 4 node-quads); block 256 = 4 waves
// wave: 2 px-tiles of 32; D[m=32 hid][n=32 px] = Wkron(32x160) @ U(160x32)
__global__ __launch_bounds__(256, 2) void gemm_kernel(
    const bf16* __restrict__ Pg, const bf16* __restrict__ Wp,
    const float* __restrict__ W2, const float* __restrict__ b2,
    float* __restrict__ out)
{
    __shared__ __align__(16) bf16  Pl[8 * 50 * D_INC];   // 12.8 KB, [row][col][ch]
    __shared__ __align__(16) float W2l[8 * HID];         // 1 KB

    const int b    = blockIdx.x;            // px chunk: 256 px
    const int n    = blockIdx.y;
    const int ob   = blockIdx.z * 8;        // node base
    const int tid  = threadIdx.x;
    const int lane = tid & 63;
    const int w    = tid >> 6;
    const int ln31 = lane & 31;
    const int qp   = lane >> 5;

    const int px0     = b * 256;
    const int r_start = px0 / 48;           // chunk spans pool rows r_start..r_start+5

    const uint4 z4 = make_uint4(0u, 0u, 0u, 0u);

    // ---- stage P tile: 8 rows (r_start-1 .. r_start+6) x 48 cols x 16ch, OOB rows = 0
    for (int u = tid; u < 768; u += 256) {
        int half = u & 1;
        int colu = (u >> 1) % 48;
        int row  = (u >> 1) / 48;
        int pr   = r_start - 1 + row;
        uint4 v  = z4;
        if (pr >= 0 && pr < HS)
            v = *(const uint4*)(Pg + ((size_t)(n * HS + pr) * WSZ + colu) * D_INC + half * 8);
        *(uint4*)(Pl + (row * 50 + colu + 1) * D_INC + half * 8) = v;
    }
    // halo cols 0 and 49 = 0 (conv zero padding)
    if (tid < 32) {
        int row  = tid >> 2;
        int side = (tid >> 1) & 1;
        int half = tid & 1;
        *(uint4*)(Pl + (row * 50 + side * 49) * D_INC + half * 8) = z4;
    }
    if (tid < 64)
        ((float4*)W2l)[tid] = ((const float4*)(W2 + ob * HID))[tid];
    __syncthreads();

    // ---- per-wave pixel fragment bases (2 tiles of 32 px) ----
    int base_ad[2];
    int pxg[2];
    #pragma unroll
    for (int t = 0; t < 2; ++t) {
        int px = px0 + w * 64 + t * 32 + ln31;
        int r  = px / 48;
        int c  = px - r * 48;
        int rl = r - r_start;                     // 0..5; tap row in LDS = rl + di
        base_ad[t] = ((rl * 50) + c) * 32 + qp * 16;   // byte addr of (di=0,dj=0,ch=8*qp)
        pxg[t] = px;
    }

    // ---- build B (pixel) fragments: lane holds U[k=16s+8qp+j][px], one ds_read_b128 each
    bf16x8 Bf[2][10];
    #pragma unroll
    for (int t = 0; t < 2; ++t) {
        #pragma unroll
        for (int s = 0; s < 9; ++s) {
            const int di = s / 3, dj = s % 3;     // compile-time tap offsets
            Bf[t][s] = *(const bf16x8*)((const char*)Pl + base_ad[t] + (di * 50 + dj) * 32);
        }
        bf16x8 bias = {};
        if (qp == 0) bias[0] = (bf16)1.0f;        // k==144 constant-1 slot
        Bf[t][9] = bias;
    }

    // ---- node loop ----
    for (int o8 = 0; o8 < 8; ++o8) {
        const int o = ob + o8;

        // A (weight) fragments: 10 coalesced dwordx4 from L2-resident Wkron
        const bf16* wp = Wp + (size_t)(o * 10) * 512 + lane * 8;
        bf16x8 Af[10];
        #pragma unroll
        for (int s = 0; s < 10; ++s)
            Af[s] = *(const bf16x8*)(wp + s * 512);

        // W2 per-lane regs: reg i -> h = (i&3) + 8*(i>>2) + 4*qp
        const float* w2b = W2l + o8 * HID + 4 * qp;
        float4 w2v0 = *(const float4*)(w2b);
        float4 w2v1 = *(const float4*)(w2b + 8);
        float4 w2v2 = *(const float4*)(w2b + 16);
        float4 w2v3 = *(const float4*)(w2b + 24);
        const float bb = b2[o];

        f32x16 acc0 = {};
        f32x16 acc1 = {};
        #pragma unroll
        for (int s = 0; s < 10; ++s) {
            acc0 = __builtin_amdgcn_mfma_f32_32x32x16_bf16(Af[s], Bf[0][s], acc0, 0, 0, 0);
            acc1 = __builtin_amdgcn_mfma_f32_32x32x16_bf16(Af[s], Bf[1][s], acc1, 0, 0, 0);
        }

        #pragma unroll
        for (int t = 0; t < 2; ++t) {
            const f32x16 a = t ? acc1 : acc0;
            float part;
            part  = fmaxf(a[0],  0.f) * w2v0.x;
            part  = fmaf(fmaxf(a[1],  0.f), w2v0.y, part);
            part  = fmaf(fmaxf(a[2],  0.f), w2v0.z, part);
            part  = fmaf(fmaxf(a[3],  0.f), w2v0.w, part);
            part  = fmaf(fmaxf(a[4],  0.f), w2v1.x, part);
            part  = fmaf(fmaxf(a[5],  0.f), w2v1.y, part);
            part  = fmaf(fmaxf(a[6],  0.f), w2v1.z, part);
            part  = fmaf(fmaxf(a[7],  0.f), w2v1.w, part);
            part  = fmaf(fmaxf(a[8],  0.f), w2v2.x, part);
            part  = fmaf(fmaxf(a[9],  0.f), w2v2.y, part);
            part  = fmaf(fmaxf(a[10], 0.f), w2v2.z, part);
            part  = fmaf(fmaxf(a[11], 0.f), w2v2.w, part);
            part  = fmaf(fmaxf(a[12], 0.f), w2v3.x, part);
            part  = fmaf(fmaxf(a[13], 0.f), w2v3.y, part);
            part  = fmaf(fmaxf(a[14], 0.f), w2v3.z, part);
            part  = fmaf(fmaxf(a[15], 0.f), w2v3.w, part);
            float tot = part + __shfl_xor(part, 32);
            tot = fmaxf(tot + bb, 0.f);
            if (qp == 0)
                out[(size_t)(n * NODES + o) * NPX + pxg[t]] = tot;
        }
    }
}

extern "C" void kernel_launch(void* const* d_in, const int* in_sizes, int n_in,
                              void* d_out, int out_size, void* d_ws, size_t ws_size,
                              hipStream_t stream)
{
    const float* x  = (const float*)d_in[0];
    const float* S  = (const float*)d_in[1];
    const float* W1 = (const float*)d_in[2];
    const float* b1 = (const float*)d_in[3];
    const float* W2 = (const float*)d_in[4];
    const float* b2 = (const float*)d_in[5];
    float* out = (float*)d_out;

    bf16* Pg = (bf16*)d_ws;                                   // 2,359,296 B
    bf16* Wp = (bf16*)((char*)d_ws + (size_t)N_B * NPX * D_INC * 2);  // 327,680 B

    wpre_kernel<<<640, 256, 0, stream>>>(S, W1, b1, Wp);
    maxpool_kernel<<<288, 256, 0, stream>>>(x, Pg);

    dim3 grid(9, N_B, 4);
    gemm_kernel<<<grid, 256, 0, stream>>>(Pg, Wp, W2, b2, out);
}

// Round 4
// 107.888 us; speedup vs baseline: 2.4842x; 1.0962x over previous
//
#include <hip/hip_runtime.h>
#include <math.h>

typedef __bf16 bf16;
typedef __bf16 bf16x8 __attribute__((ext_vector_type(8)));
typedef float  f32x16 __attribute__((ext_vector_type(16)));

#define D_INC 16
#define NODES 32
#define HID   32
#define HS    48
#define WSZ   48
#define NPX   (HS*WSZ)     // 2304
#define H_IN  96
#define W_IN  96
#define N_B   32

#define MP_BLOCKS   1152   // 32*48*48*4 / 256
#define WPRE_BLOCKS 640    // 163840 / 256

// ---------------- Kernel P+W merged ----------------
// blocks [0, MP_BLOCKS): maxpool 3x3 s2 p1 -> Pg (N,48,48,16ch) bf16,
//   one thread per (pixel, 4-channel quad): 36 loads/thread, 4x parallelism
// blocks [MP_BLOCKS, MP_BLOCKS+WPRE_BLOCKS): Wkron precompute
__global__ __launch_bounds__(256) void pre_kernel(
    const float* __restrict__ x, bf16* __restrict__ Pg,
    const float* __restrict__ S, const float* __restrict__ W1,
    const float* __restrict__ b1, bf16* __restrict__ Wp)
{
    if (blockIdx.x < MP_BLOCKS) {
        int idx = blockIdx.x * 256 + threadIdx.x;   // (n, r, c, q) q = ch-quad
        int q = idx & 3;
        int c = (idx >> 2) % WSZ;
        int t = (idx >> 2) / WSZ;
        int r = t % HS;
        int n = t / HS;

        const float* xb = x + ((size_t)(n * D_INC + q * 4)) * (H_IN * W_IN);

        float m0 = -INFINITY, m1 = -INFINITY, m2 = -INFINITY, m3 = -INFINITY;
        #pragma unroll
        for (int dr = 0; dr < 3; ++dr) {
            int xr = 2 * r - 1 + dr;
            if (xr < 0) continue;                   // xr <= 95 always
            #pragma unroll
            for (int dc = 0; dc < 3; ++dc) {
                int xc = 2 * c - 1 + dc;
                if (xc < 0) continue;               // xc <= 95 always
                const float* p = xb + xr * W_IN + xc;
                m0 = fmaxf(m0, p[0 * H_IN * W_IN]);
                m1 = fmaxf(m1, p[1 * H_IN * W_IN]);
                m2 = fmaxf(m2, p[2 * H_IN * W_IN]);
                m3 = fmaxf(m3, p[3 * H_IN * W_IN]);
            }
        }
        union { bf16 h[4]; uint2 u; } v;
        v.h[0] = (bf16)m0; v.h[1] = (bf16)m1; v.h[2] = (bf16)m2; v.h[3] = (bf16)m3;
        // byte addr = idx*8: per-wave 512 B contiguous
        *(uint2*)(Pg + (size_t)idx * 4) = v.u;
    } else {
        // Wkron[o][s][qp][h][j] = S[o,d,t]*W1[o,d,h], k = 16s+8qp+j
        // k==144 -> b1[o,h]; k>144 -> 0. Lane-linear for A-fragment loads.
        int idx = (blockIdx.x - MP_BLOCKS) * 256 + threadIdx.x;
        if (idx >= NODES * 10 * 2 * HID * 8) return;
        int j  = idx & 7;
        int h  = (idx >> 3) & 31;
        int qp = (idx >> 8) & 1;
        int os = idx >> 9;
        int s  = os % 10;
        int o  = os / 10;
        int k  = 16 * s + 8 * qp + j;
        float v = 0.f;
        if (k < 144) {
            int t = k >> 4;
            int d = k & 15;
            v = S[(o * D_INC + d) * 9 + t] * W1[(o * D_INC + d) * HID + h];
        } else if (k == 144) {
            v = b1[o * HID + h];
        }
        Wp[idx] = (bf16)v;
    }
}

// ---------------- Kernel G: fused (conv+MLP1) GEMM via MFMA + MLP2 epilogue ----------------
// grid (9 px-chunks, 32 batch, 8 node-quads of 4); block 256 = 4 waves
// wave: 2 px-tiles of 32; D[m=32 hid][n=32 px] = Wkron(32x160) @ U(160x32)
__global__ __launch_bounds__(256, 2) void gemm_kernel(
    const bf16* __restrict__ Pg, const bf16* __restrict__ Wp,
    const float* __restrict__ W2, const float* __restrict__ b2,
    float* __restrict__ out)
{
    __shared__ __align__(16) bf16  Pl[8 * 50 * D_INC];   // 12.8 KB, [row][col][ch]
    __shared__ __align__(16) float W2l[4 * HID];         // 0.5 KB

    const int b    = blockIdx.x;            // px chunk: 256 px
    const int n    = blockIdx.y;
    const int ob   = blockIdx.z * 4;        // node base
    const int tid  = threadIdx.x;
    const int lane = tid & 63;
    const int w    = tid >> 6;
    const int ln31 = lane & 31;
    const int qp   = lane >> 5;

    const int px0     = b * 256;
    const int r_start = px0 / 48;           // chunk spans pool rows r_start..r_start+5

    const uint4 z4 = make_uint4(0u, 0u, 0u, 0u);

    // ---- stage P tile: 8 rows (r_start-1 .. r_start+6) x 48 cols x 16ch, OOB rows = 0
    for (int u = tid; u < 768; u += 256) {
        int half = u & 1;
        int colu = (u >> 1) % 48;
        int row  = (u >> 1) / 48;
        int pr   = r_start - 1 + row;
        uint4 v  = z4;
        if (pr >= 0 && pr < HS)
            v = *(const uint4*)(Pg + ((size_t)(n * HS + pr) * WSZ + colu) * D_INC + half * 8);
        *(uint4*)(Pl + (row * 50 + colu + 1) * D_INC + half * 8) = v;
    }
    // halo cols 0 and 49 = 0 (conv zero padding)
    if (tid < 32) {
        int row  = tid >> 2;
        int side = (tid >> 1) & 1;
        int half = tid & 1;
        *(uint4*)(Pl + (row * 50 + side * 49) * D_INC + half * 8) = z4;
    }
    if (tid < 32)
        ((float4*)W2l)[tid] = ((const float4*)(W2 + ob * HID))[tid];
    __syncthreads();

    // ---- per-wave pixel fragment bases (2 tiles of 32 px) ----
    int base_ad[2];
    int pxg[2];
    #pragma unroll
    for (int t = 0; t < 2; ++t) {
        int px = px0 + w * 64 + t * 32 + ln31;
        int r  = px / 48;
        int c  = px - r * 48;
        int rl = r - r_start;                     // 0..5; tap row in LDS = rl + di
        base_ad[t] = ((rl * 50) + c) * 32 + qp * 16;   // byte addr of (di=0,dj=0,ch=8*qp)
        pxg[t] = px;
    }

    // ---- build B (pixel) fragments: lane holds U[k=16s+8qp+j][px], one ds_read_b128 each
    bf16x8 Bf[2][10];
    #pragma unroll
    for (int t = 0; t < 2; ++t) {
        #pragma unroll
        for (int s = 0; s < 9; ++s) {
            const int di = s / 3, dj = s % 3;     // compile-time tap offsets
            Bf[t][s] = *(const bf16x8*)((const char*)Pl + base_ad[t] + (di * 50 + dj) * 32);
        }
        bf16x8 bias = {};
        if (qp == 0) bias[0] = (bf16)1.0f;        // k==144 constant-1 slot
        Bf[t][9] = bias;
    }

    // ---- node loop (4 nodes/block) ----
    for (int o4 = 0; o4 < 4; ++o4) {
        const int o = ob + o4;

        // A (weight) fragments: 10 coalesced dwordx4 from L2-resident Wkron
        const bf16* wp = Wp + (size_t)(o * 10) * 512 + lane * 8;
        bf16x8 Af[10];
        #pragma unroll
        for (int s = 0; s < 10; ++s)
            Af[s] = *(const bf16x8*)(wp + s * 512);

        // W2 per-lane regs: reg i -> h = (i&3) + 8*(i>>2) + 4*qp
        const float* w2b = W2l + o4 * HID + 4 * qp;
        float4 w2v0 = *(const float4*)(w2b);
        float4 w2v1 = *(const float4*)(w2b + 8);
        float4 w2v2 = *(const float4*)(w2b + 16);
        float4 w2v3 = *(const float4*)(w2b + 24);
        const float bb = b2[o];

        f32x16 acc0 = {};
        f32x16 acc1 = {};
        #pragma unroll
        for (int s = 0; s < 10; ++s) {
            acc0 = __builtin_amdgcn_mfma_f32_32x32x16_bf16(Af[s], Bf[0][s], acc0, 0, 0, 0);
            acc1 = __builtin_amdgcn_mfma_f32_32x32x16_bf16(Af[s], Bf[1][s], acc1, 0, 0, 0);
        }

        #pragma unroll
        for (int t = 0; t < 2; ++t) {
            const f32x16 a = t ? acc1 : acc0;
            float part;
            part  = fmaxf(a[0],  0.f) * w2v0.x;
            part  = fmaf(fmaxf(a[1],  0.f), w2v0.y, part);
            part  = fmaf(fmaxf(a[2],  0.f), w2v0.z, part);
            part  = fmaf(fmaxf(a[3],  0.f), w2v0.w, part);
            part  = fmaf(fmaxf(a[4],  0.f), w2v1.x, part);
            part  = fmaf(fmaxf(a[5],  0.f), w2v1.y, part);
            part  = fmaf(fmaxf(a[6],  0.f), w2v1.z, part);
            part  = fmaf(fmaxf(a[7],  0.f), w2v1.w, part);
            part  = fmaf(fmaxf(a[8],  0.f), w2v2.x, part);
            part  = fmaf(fmaxf(a[9],  0.f), w2v2.y, part);
            part  = fmaf(fmaxf(a[10], 0.f), w2v2.z, part);
            part  = fmaf(fmaxf(a[11], 0.f), w2v2.w, part);
            part  = fmaf(fmaxf(a[12], 0.f), w2v3.x, part);
            part  = fmaf(fmaxf(a[13], 0.f), w2v3.y, part);
            part  = fmaf(fmaxf(a[14], 0.f), w2v3.z, part);
            part  = fmaf(fmaxf(a[15], 0.f), w2v3.w, part);
            float tot = part + __shfl_xor(part, 32);
            tot = fmaxf(tot + bb, 0.f);
            if (qp == 0)
                out[(size_t)(n * NODES + o) * NPX + pxg[t]] = tot;
        }
    }
}

extern "C" void kernel_launch(void* const* d_in, const int* in_sizes, int n_in,
                              void* d_out, int out_size, void* d_ws, size_t ws_size,
                              hipStream_t stream)
{
    const float* x  = (const float*)d_in[0];
    const float* S  = (const float*)d_in[1];
    const float* W1 = (const float*)d_in[2];
    const float* b1 = (const float*)d_in[3];
    const float* W2 = (const float*)d_in[4];
    const float* b2 = (const float*)d_in[5];
    float* out = (float*)d_out;

    bf16* Pg = (bf16*)d_ws;                                   // 2,359,296 B
    bf16* Wp = (bf16*)((char*)d_ws + (size_t)N_B * NPX * D_INC * 2);  // 327,680 B

    pre_kernel<<<MP_BLOCKS + WPRE_BLOCKS, 256, 0, stream>>>(x, Pg, S, W1, b1, Wp);

    dim3 grid(9, N_B, 8);
    gemm_kernel<<<grid, 256, 0, stream>>>(Pg, Wp, W2, b2, out);
}